// Round 1
// baseline (2097.149 us; speedup 1.0000x reference)
//
#include <hip/hip_runtime.h>
#include <math.h>

// Problem constants (from setup_inputs: spec (32,128,256) fp32, basis (1024,256) fp32,
// n_iter=30, pad=0, stride=4 -> 63 windows).
#define NB     256     // N_BASIS
#define NF     128     // N_FREQ
#define NT     8       // N_TIME
#define FT     1024    // NF*NT
#define BROWS  32      // batch rows per window
#define NW     63      // number of windows ((256-8)/4 + 1)
#define TORIG  256     // original time length
#define LAMF   0.2f
#define LRF    1e-3f

// ---------------------------------------------------------------------------
// Kernel 1: G = basis^T @ basis  (256x256), one-time. block = output row k1.
// ---------------------------------------------------------------------------
__global__ __launch_bounds__(256) void gram_kernel(const float* __restrict__ basis,
                                                   float* __restrict__ G)
{
    const int k1 = blockIdx.x;
    const int k2 = threadIdx.x;
    float acc = 0.f;
    const float* c1 = basis + k1;
    const float* c2 = basis + k2;
    #pragma unroll 4
    for (int j = 0; j < FT; ++j)
        acc = fmaf(c1[j * NB], c2[j * NB], acc);
    G[k1 * NB + k2] = acc;
}

// ---------------------------------------------------------------------------
// Kernel 2: one block per window. 512 threads.
// Thread tile: 4 rows (b0..b0+3) x 4 cols (k0..k0+3) of the (32,256) coef.
//   bg = tid>>6 (0..7) -> b0 = 4*bg ; kg = tid&63 -> k0 = 4*kg
// coef mirrored in LDS for the GEMM; m, v, xB, acc in registers.
// Loss scalars accumulated in fp64 to keep the convergence statistic tight.
// ---------------------------------------------------------------------------
__global__ __launch_bounds__(512, 2) void window_kernel(
    const float* __restrict__ spec,
    const float* __restrict__ basis,
    const float* __restrict__ G,
    const int* __restrict__ p_niter,
    const int* __restrict__ p_pad,
    const int* __restrict__ p_stride,
    float* __restrict__ out)
{
    __shared__ float  s_coef[BROWS][NB];   // 32 KB
    __shared__ float  s_xt[BROWS][NB];     // 32 KB (x tile, 1/4 of window)
    __shared__ float  s_mn[BROWS];
    __shared__ float  s_rng[BROWS];
    __shared__ double s_red[8][4];
    __shared__ double s_sx2;
    __shared__ float  s_loss;

    const int w      = blockIdx.x;
    const int tid    = threadIdx.x;
    const int n_iter = p_niter[0];
    const int pad    = p_pad[0];
    const int stride = p_stride[0];
    const int t0     = w * stride - pad;   // original-time index of window element t=0

    const int kg = tid & 63;
    const int bg = tid >> 6;
    const int k0 = kg * 4;
    const int b0 = bg * 4;

    // ---- per-row min/max over the 1024 window elements (raw spec) ----
    {
        const int b = tid >> 4;       // 32 rows x 16 threads
        const int p = tid & 15;
        float mn = __builtin_inff(), mx = -__builtin_inff();
        const float* srow = spec + (size_t)b * NF * TORIG;
        for (int j = p; j < FT; j += 16) {
            const int f = j >> 3, t = j & 7;
            const int tq = t0 + t;
            const float v = (tq >= 0 && tq < TORIG) ? srow[f * TORIG + tq] : 0.f;
            mn = fminf(mn, v); mx = fmaxf(mx, v);
        }
        #pragma unroll
        for (int off = 8; off; off >>= 1) {
            mn = fminf(mn, __shfl_down(mn, off));
            mx = fmaxf(mx, __shfl_down(mx, off));
        }
        if (p == 0) { s_mn[b] = mn; s_rng[b] = mx - mn; }
    }
    __syncthreads();

    // ---- xB = xnorm @ basis (into registers), and sum(x^2) ----
    float xB[4][4];
    #pragma unroll
    for (int i = 0; i < 4; ++i)
        #pragma unroll
        for (int j = 0; j < 4; ++j) xB[i][j] = 0.f;
    double sx2p = 0.0;

    for (int jt = 0; jt < 4; ++jt) {
        // stage normalized x tile (32 x 256)
        for (int e = tid; e < BROWS * 256; e += 512) {
            const int bb = e >> 8, jj = e & 255;
            const int j = jt * 256 + jj;
            const int f = j >> 3, t = j & 7;
            const int tq = t0 + t;
            float v = (tq >= 0 && tq < TORIG) ? spec[((size_t)bb * NF + f) * TORIG + tq] : 0.f;
            v = (v - s_mn[bb]) / s_rng[bb];
            s_xt[bb][jj] = v;
            sx2p += (double)v * (double)v;
        }
        __syncthreads();
        for (int j = 0; j < 256; ++j) {
            const float4 bv = *(const float4*)(basis + ((size_t)(jt * 256 + j)) * NB + k0);
            #pragma unroll
            for (int i = 0; i < 4; ++i) {
                const float xv = s_xt[b0 + i][j];
                xB[i][0] = fmaf(xv, bv.x, xB[i][0]);
                xB[i][1] = fmaf(xv, bv.y, xB[i][1]);
                xB[i][2] = fmaf(xv, bv.z, xB[i][2]);
                xB[i][3] = fmaf(xv, bv.w, xB[i][3]);
            }
        }
        __syncthreads();
    }

    // reduce sx2 across block
    #pragma unroll
    for (int off = 32; off; off >>= 1) sx2p += __shfl_down(sx2p, off);
    if ((tid & 63) == 0) s_red[tid >> 6][0] = sx2p;
    __syncthreads();
    if (tid == 0) {
        double s = 0.0;
        #pragma unroll
        for (int i = 0; i < 8; ++i) s += s_red[i][0];
        s_sx2 = s;
    }

    // ---- init coef / Adam state ----
    const float C0 = 0.5f / (float)NB;   // 0.001953125
    float coef[4][4], m_[4][4], v_[4][4];
    #pragma unroll
    for (int i = 0; i < 4; ++i)
        #pragma unroll
        for (int j = 0; j < 4; ++j) { coef[i][j] = C0; m_[i][j] = 0.f; v_[i][j] = 0.f; }
    #pragma unroll
    for (int i = 0; i < 4; ++i)
        *(float4*)&s_coef[b0 + i][k0] = make_float4(C0, C0, C0, C0);
    __syncthreads();

    const float c1 = 2.0f / 32768.0f;       // mse grad scale
    const float c2 = LAMF / 8192.0f;        // L1 grad scale
    float b1p = 1.f, b2p = 1.f;
    float old_loss = 1e-10f;

    for (int it = 0; it < n_iter; ++it) {
        // ---- acc = coef @ G  (using G symmetry: read G rows k) ----
        float acc[4][4];
        #pragma unroll
        for (int i = 0; i < 4; ++i)
            #pragma unroll
            for (int j = 0; j < 4; ++j) acc[i][j] = 0.f;

        const float* g0p = G + (size_t)(k0 + 0) * NB;
        const float* g1p = G + (size_t)(k0 + 1) * NB;
        const float* g2p = G + (size_t)(k0 + 2) * NB;
        const float* g3p = G + (size_t)(k0 + 3) * NB;

        for (int kk = 0; kk < NB; kk += 4) {
            const float4 a0 = *(const float4*)&s_coef[b0 + 0][kk];
            const float4 a1 = *(const float4*)&s_coef[b0 + 1][kk];
            const float4 a2 = *(const float4*)&s_coef[b0 + 2][kk];
            const float4 a3 = *(const float4*)&s_coef[b0 + 3][kk];
            const float4 g0 = *(const float4*)(g0p + kk);
            const float4 g1 = *(const float4*)(g1p + kk);
            const float4 g2 = *(const float4*)(g2p + kk);
            const float4 g3 = *(const float4*)(g3p + kk);
            #define ACC_ROW(i, a)                                              \
                acc[i][0] = fmaf(a.x, g0.x, acc[i][0]);                        \
                acc[i][0] = fmaf(a.y, g0.y, acc[i][0]);                        \
                acc[i][0] = fmaf(a.z, g0.z, acc[i][0]);                        \
                acc[i][0] = fmaf(a.w, g0.w, acc[i][0]);                        \
                acc[i][1] = fmaf(a.x, g1.x, acc[i][1]);                        \
                acc[i][1] = fmaf(a.y, g1.y, acc[i][1]);                        \
                acc[i][1] = fmaf(a.z, g1.z, acc[i][1]);                        \
                acc[i][1] = fmaf(a.w, g1.w, acc[i][1]);                        \
                acc[i][2] = fmaf(a.x, g2.x, acc[i][2]);                        \
                acc[i][2] = fmaf(a.y, g2.y, acc[i][2]);                        \
                acc[i][2] = fmaf(a.z, g2.z, acc[i][2]);                        \
                acc[i][2] = fmaf(a.w, g2.w, acc[i][2]);                        \
                acc[i][3] = fmaf(a.x, g3.x, acc[i][3]);                        \
                acc[i][3] = fmaf(a.y, g3.y, acc[i][3]);                        \
                acc[i][3] = fmaf(a.z, g3.z, acc[i][3]);                        \
                acc[i][3] = fmaf(a.w, g3.w, acc[i][3]);
            ACC_ROW(0, a0) ACC_ROW(1, a1) ACC_ROW(2, a2) ACC_ROW(3, a3)
            #undef ACC_ROW
        }

        // ---- loss partials (fp64 accumulate) ----
        double qp = 0.0, cp = 0.0, rp = 0.0;
        #pragma unroll
        for (int i = 0; i < 4; ++i)
            #pragma unroll
            for (int j = 0; j < 4; ++j) {
                const float cf = coef[i][j];
                qp += (double)cf * (double)acc[i][j];
                cp += (double)cf * (double)xB[i][j];
                rp += (double)fabsf(cf);
            }
        #pragma unroll
        for (int off = 32; off; off >>= 1) {
            qp += __shfl_down(qp, off);
            cp += __shfl_down(cp, off);
            rp += __shfl_down(rp, off);
        }
        if ((tid & 63) == 0) {
            s_red[tid >> 6][0] = qp; s_red[tid >> 6][1] = cp; s_red[tid >> 6][2] = rp;
        }
        __syncthreads();
        if (tid == 0) {
            double Q = 0, C = 0, R = 0;
            #pragma unroll
            for (int i = 0; i < 8; ++i) { Q += s_red[i][0]; C += s_red[i][1]; R += s_red[i][2]; }
            const double mse = (Q - 2.0 * C + s_sx2) / 32768.0;
            s_loss = (float)(mse + (double)LAMF * (R / 8192.0));
        }
        __syncthreads();
        const float loss = s_loss;

        // ---- Adam update (update applied, THEN convergence break) ----
        b1p *= 0.9f; b2p *= 0.999f;
        const float bc1 = 1.f - b1p, bc2 = 1.f - b2p;
        #pragma unroll
        for (int i = 0; i < 4; ++i) {
            #pragma unroll
            for (int j = 0; j < 4; ++j) {
                const float cf = coef[i][j];
                const float sgn = (cf > 0.f) ? 1.f : ((cf < 0.f) ? -1.f : 0.f);
                const float g = c1 * (acc[i][j] - xB[i][j]) + c2 * sgn;
                m_[i][j] = 0.9f * m_[i][j] + 0.1f * g;
                v_[i][j] = 0.999f * v_[i][j] + 0.001f * g * g;
                const float mhat = m_[i][j] / bc1;
                const float vhat = v_[i][j] / bc2;
                coef[i][j] = cf - LRF * mhat / (sqrtf(vhat) + 1e-8f);
            }
            *(float4*)&s_coef[b0 + i][k0] =
                make_float4(coef[i][0], coef[i][1], coef[i][2], coef[i][3]);
        }
        __syncthreads();

        const float stat = fabsf(old_loss - loss) / old_loss;
        old_loss = loss;
        if (stat < 1e-3f) break;   // block-uniform
    }

    // ---- write out: out[b][k][w], shape (32,256,63) ----
    #pragma unroll
    for (int i = 0; i < 4; ++i)
        #pragma unroll
        for (int j = 0; j < 4; ++j)
            out[((size_t)(b0 + i) * NB + (k0 + j)) * NW + w] = coef[i][j];
}

// ---------------------------------------------------------------------------
extern "C" void kernel_launch(void* const* d_in, const int* in_sizes, int n_in,
                              void* d_out, int out_size, void* d_ws, size_t ws_size,
                              hipStream_t stream)
{
    const float* spec   = (const float*)d_in[0];
    const float* basis  = (const float*)d_in[1];
    const int* p_niter  = (const int*)d_in[2];
    const int* p_pad    = (const int*)d_in[3];
    const int* p_stride = (const int*)d_in[4];
    float* G   = (float*)d_ws;          // 256*256*4 = 256 KB scratch
    float* out = (float*)d_out;

    gram_kernel<<<dim3(NB), dim3(NB), 0, stream>>>(basis, G);
    window_kernel<<<dim3(NW), dim3(512), 0, stream>>>(spec, basis, G,
                                                      p_niter, p_pad, p_stride, out);
}

// Round 2
// 455.945 us; speedup vs baseline: 4.5996x; 4.5996x over previous
//
#include <hip/hip_runtime.h>
#include <math.h>

// SparseCoding on MI355X, round 2.
// spec (32,128,256) fp32, basis (1024,256) fp32, n_iter=30, pad=0, stride=4 -> 63 windows.
// Restructure vs R1: 4 blocks per window (8 batch-rows each) -> 252 blocks;
// G tile held in registers across all iterations (K-split over the 8 waves);
// per-iteration cross-block loss sync via device-scope atomics in d_ws.
#define NB     256
#define NF     128
#define NT     8
#define FT     1024
#define NW     63
#define TORIG  256
#define MAXIT  48     // >= n_iter (30); sizes the sync buffers
#define RPB    8      // batch rows per block
#define NBLK   4      // blocks per window

// ---------------------------------------------------------------------------
// G = basis^T @ basis (256x256), one-time.
// ---------------------------------------------------------------------------
__global__ __launch_bounds__(256) void gram_kernel(const float* __restrict__ basis,
                                                   float* __restrict__ G)
{
    const int k1 = blockIdx.x, k2 = threadIdx.x;
    float acc = 0.f;
    const float* c1 = basis + k1;
    const float* c2 = basis + k2;
    #pragma unroll 8
    for (int j = 0; j < FT; ++j) acc = fmaf(c1[j * NB], c2[j * NB], acc);
    G[k1 * NB + k2] = acc;
}

// ---------------------------------------------------------------------------
// One block per (window, row-quarter). 512 threads = 8 waves.
// wave ks (0..7): owns K-slice [32ks,32ks+32) of the GEMM AND local row b=ks.
// lane kg (0..63): owns output cols 4kg..4kg+3.
// G[32ks+kl][4kg+j] lives in 32 float4 registers for the whole kernel.
// ---------------------------------------------------------------------------
__global__ __launch_bounds__(512, 2) void window_kernel(
    const float* __restrict__ spec,
    const float* __restrict__ basis,
    const float* __restrict__ G,
    const int* __restrict__ p_niter,
    const int* __restrict__ p_pad,
    const int* __restrict__ p_stride,
    double* __restrict__ sxbuf,          // [NW][NBLK] sum(x^2) partials
    double* __restrict__ gpart,          // [MAXIT][NW][NBLK][2] (Q-2C, R)
    unsigned int* __restrict__ gcnt,     // [MAXIT][NW] arrival counters (memset 0)
    float* __restrict__ out)             // (32,256,63)
{
    __shared__ float  s_part[RPB * RPB * 64 * 4];  // 64KB; first 32KB doubles as s_xn[8][1024]
    __shared__ float  s_coef[RPB][NB];             // 8KB
    __shared__ float  s_mn[RPB], s_rng[RPB];
    __shared__ double s_red[8][2];
    __shared__ int    s_stop;

    const int w      = blockIdx.x >> 2;
    const int q      = blockIdx.x & 3;
    const int tid    = threadIdx.x;
    const int ks     = tid >> 6;
    const int kg     = tid & 63;
    const int n_iter = p_niter[0];
    const int t0     = w * p_stride[0] - p_pad[0];

    // ---- per-row min/max over the 1024 raw window elements ----
    {
        const float* srow = spec + (size_t)(q * RPB + ks) * NF * TORIG;
        float mn = __builtin_inff(), mx = -__builtin_inff();
        for (int j = kg; j < FT; j += 64) {
            const int f = j >> 3, t = j & 7, tq = t0 + t;
            const float v = (tq >= 0 && tq < TORIG) ? srow[f * TORIG + tq] : 0.f;
            mn = fminf(mn, v); mx = fmaxf(mx, v);
        }
        #pragma unroll
        for (int off = 32; off; off >>= 1) {
            mn = fminf(mn, __shfl_down(mn, off));
            mx = fmaxf(mx, __shfl_down(mx, off));
        }
        if (kg == 0) { s_mn[ks] = mn; s_rng[ks] = mx - mn; }
    }
    __syncthreads();

    // ---- stage normalized x (8x1024) into s_xn (= s_part), accumulate sum(x^2) ----
    float* s_xn = s_part;
    double sx2p = 0.0;
    #pragma unroll
    for (int i = 0; i < 16; ++i) {
        const int e = i * 512 + tid;
        const int b = e >> 10, jj = e & 1023;
        const int f = jj >> 3, t = jj & 7, tq = t0 + t;
        float v = (tq >= 0 && tq < TORIG)
                ? spec[((size_t)(q * RPB + b) * NF + f) * TORIG + tq] : 0.f;
        v = (v - s_mn[b]) / s_rng[b];
        s_xn[b * 1024 + jj] = v;
        sx2p += (double)v * (double)v;
    }
    __syncthreads();

    // ---- xB partials: jj in [128ks, 128ks+128), cols 4kg..+3, all 8 rows ----
    float xbp[RPB][4];
    #pragma unroll
    for (int b = 0; b < RPB; ++b)
        #pragma unroll
        for (int j = 0; j < 4; ++j) xbp[b][j] = 0.f;

    for (int i = 0; i < 128; ++i) {
        const int jj = ks * 128 + i;
        const float4 bv = *(const float4*)(basis + (size_t)jj * NB + 4 * kg);
        #pragma unroll
        for (int b = 0; b < RPB; ++b) {
            const float xv = s_xn[b * 1024 + jj];
            xbp[b][0] = fmaf(xv, bv.x, xbp[b][0]);
            xbp[b][1] = fmaf(xv, bv.y, xbp[b][1]);
            xbp[b][2] = fmaf(xv, bv.z, xbp[b][2]);
            xbp[b][3] = fmaf(xv, bv.w, xbp[b][3]);
        }
    }

    // block partial of sum(x^2) -> sxbuf (released later by the it=0 counter)
    #pragma unroll
    for (int off = 32; off; off >>= 1) sx2p += __shfl_down(sx2p, off);
    if (kg == 0) s_red[ks][0] = sx2p;
    __syncthreads();              // everyone done reading s_xn; s_red ready
    if (tid == 0) {
        double s = 0.0;
        #pragma unroll
        for (int i = 0; i < 8; ++i) s += s_red[i][0];
        sxbuf[w * NBLK + q] = s;
    }

    // xB reduction through s_part (overwrites s_xn)
    #pragma unroll
    for (int b = 0; b < RPB; ++b)
        *(float4*)&s_part[((ks * RPB + b) * 64 + kg) * 4] =
            make_float4(xbp[b][0], xbp[b][1], xbp[b][2], xbp[b][3]);
    __syncthreads();
    float xB[4] = {0.f, 0.f, 0.f, 0.f};
    #pragma unroll
    for (int k2 = 0; k2 < 8; ++k2) {
        const float4 p4 = *(const float4*)&s_part[((k2 * RPB + ks) * 64 + kg) * 4];
        xB[0] += p4.x; xB[1] += p4.y; xB[2] += p4.z; xB[3] += p4.w;
    }

    // ---- G fragment into registers (held for the whole loop) ----
    float4 g[32];
    #pragma unroll
    for (int kl = 0; kl < 32; ++kl)
        g[kl] = *(const float4*)(G + (size_t)(32 * ks + kl) * NB + 4 * kg);

    // ---- init coef / Adam ----
    const float C0 = 0.5f / 256.f;
    float cf[4] = {C0, C0, C0, C0}, m_[4] = {0,0,0,0}, v_[4] = {0,0,0,0};
    *(float4*)&s_coef[ks][4 * kg] = make_float4(C0, C0, C0, C0);
    if (tid == 0) s_stop = 0;
    float b1p = 1.f, b2p = 1.f;
    float old_loss = 1e-10f;      // tid0 only
    double sxtot = 0.0;           // tid0 only
    const float c1 = 2.f / 32768.f, c2 = 0.2f / 8192.f;

    for (int it = 0; it < n_iter; ++it) {
        __syncthreads();          // s_coef writes visible; s_part free

        // acc partials over own K-slice, all 8 rows x own 4 cols (pure registers+LDS bcast)
        float pacc[RPB][4];
        #pragma unroll
        for (int b = 0; b < RPB; ++b)
            #pragma unroll
            for (int j = 0; j < 4; ++j) pacc[b][j] = 0.f;

        #pragma unroll
        for (int t = 0; t < 8; ++t) {
            float4 c4[RPB];
            #pragma unroll
            for (int b = 0; b < RPB; ++b)
                c4[b] = *(const float4*)&s_coef[b][32 * ks + 4 * t];
            #pragma unroll
            for (int u = 0; u < 4; ++u) {
                const float4 gv = g[4 * t + u];
                #pragma unroll
                for (int b = 0; b < RPB; ++b) {
                    const float cc = (u == 0) ? c4[b].x : (u == 1) ? c4[b].y
                                     : (u == 2) ? c4[b].z : c4[b].w;
                    pacc[b][0] = fmaf(cc, gv.x, pacc[b][0]);
                    pacc[b][1] = fmaf(cc, gv.y, pacc[b][1]);
                    pacc[b][2] = fmaf(cc, gv.z, pacc[b][2]);
                    pacc[b][3] = fmaf(cc, gv.w, pacc[b][3]);
                }
            }
        }

        // K-reduction through LDS
        #pragma unroll
        for (int b = 0; b < RPB; ++b)
            *(float4*)&s_part[((ks * RPB + b) * 64 + kg) * 4] =
                make_float4(pacc[b][0], pacc[b][1], pacc[b][2], pacc[b][3]);
        __syncthreads();
        float a4[4] = {0.f, 0.f, 0.f, 0.f};
        #pragma unroll
        for (int k2 = 0; k2 < 8; ++k2) {
            const float4 p4 = *(const float4*)&s_part[((k2 * RPB + ks) * 64 + kg) * 4];
            a4[0] += p4.x; a4[1] += p4.y; a4[2] += p4.z; a4[3] += p4.w;
        }

        // loss partials (fp64): Q - 2C and R over this thread's 4 coefs
        double qc = 0.0, rr = 0.0;
        #pragma unroll
        for (int j = 0; j < 4; ++j) {
            qc += (double)cf[j] * (double)a4[j] - 2.0 * (double)cf[j] * (double)xB[j];
            rr += (double)fabsf(cf[j]);
        }
        #pragma unroll
        for (int off = 32; off; off >>= 1) {
            qc += __shfl_down(qc, off);
            rr += __shfl_down(rr, off);
        }
        if (kg == 0) { s_red[ks][0] = qc; s_red[ks][1] = rr; }
        __syncthreads();

        if (tid == 0) {
            double Q = 0.0, R = 0.0;
            #pragma unroll
            for (int i = 0; i < 8; ++i) { Q += s_red[i][0]; R += s_red[i][1]; }
            const size_t pb = ((size_t)it * NW + w) * NBLK;
            gpart[(pb + q) * 2 + 0] = Q;
            gpart[(pb + q) * 2 + 1] = R;
            __threadfence();                               // release partials
            atomicAdd(&gcnt[it * NW + w], 1u);
            while (__hip_atomic_load(&gcnt[it * NW + w], __ATOMIC_ACQUIRE,
                                     __HIP_MEMORY_SCOPE_AGENT) < (unsigned)NBLK) {
                __builtin_amdgcn_s_sleep(1);
            }
            double Qt = 0.0, Rt = 0.0;
            #pragma unroll
            for (int i = 0; i < NBLK; ++i) {
                Qt += gpart[(pb + i) * 2 + 0];
                Rt += gpart[(pb + i) * 2 + 1];
            }
            if (it == 0)
                sxtot = sxbuf[w * NBLK + 0] + sxbuf[w * NBLK + 1] +
                        sxbuf[w * NBLK + 2] + sxbuf[w * NBLK + 3];
            const float loss = (float)((Qt + sxtot) / 32768.0 + 0.2 * (Rt / 8192.0));
            const float stat = fabsf(old_loss - loss) / old_loss;
            old_loss = loss;
            s_stop = (stat < 1e-3f) ? 1 : 0;
        }
        __syncthreads();

        // Adam update (always applied at the triggering step, matching reference)
        b1p *= 0.9f; b2p *= 0.999f;
        const float bc1 = 1.f - b1p, bc2 = 1.f - b2p;
        #pragma unroll
        for (int j = 0; j < 4; ++j) {
            const float c_ = cf[j];
            const float sgn = (c_ > 0.f) ? 1.f : ((c_ < 0.f) ? -1.f : 0.f);
            const float gg = c1 * (a4[j] - xB[j]) + c2 * sgn;
            m_[j] = 0.9f * m_[j] + 0.1f * gg;
            v_[j] = 0.999f * v_[j] + 0.001f * gg * gg;
            cf[j] = c_ - 1e-3f * (m_[j] / bc1) / (sqrtf(v_[j] / bc2) + 1e-8f);
        }
        *(float4*)&s_coef[ks][4 * kg] = make_float4(cf[0], cf[1], cf[2], cf[3]);

        if (s_stop) break;
    }

    // ---- out[b][k][w], b = q*8+ks, k = 4kg+j ----
    #pragma unroll
    for (int j = 0; j < 4; ++j)
        out[((size_t)(q * RPB + ks) * NB + 4 * kg + j) * NW + w] = cf[j];
}

// ---------------------------------------------------------------------------
extern "C" void kernel_launch(void* const* d_in, const int* in_sizes, int n_in,
                              void* d_out, int out_size, void* d_ws, size_t ws_size,
                              hipStream_t stream)
{
    const float* spec   = (const float*)d_in[0];
    const float* basis  = (const float*)d_in[1];
    const int* p_niter  = (const int*)d_in[2];
    const int* p_pad    = (const int*)d_in[3];
    const int* p_stride = (const int*)d_in[4];
    float* out = (float*)d_out;

    char* ws = (char*)d_ws;
    float*        G     = (float*)ws;                               // 256 KB
    double*       sxbuf = (double*)(ws + 262144);                   // 2016 B (pad 4 KB)
    double*       gpart = (double*)(ws + 262144 + 4096);            // 48*63*4*2*8 = 193536 B
    unsigned int* gcnt  = (unsigned int*)(ws + 262144 + 4096 + 193536); // 12096 B

    hipMemsetAsync(gcnt, 0, MAXIT * NW * sizeof(unsigned int), stream);
    gram_kernel<<<dim3(NB), dim3(NB), 0, stream>>>(basis, G);
    window_kernel<<<dim3(NW * NBLK), dim3(512), 0, stream>>>(
        spec, basis, G, p_niter, p_pad, p_stride, sxbuf, gpart, gcnt, out);
}

// Round 4
// 366.722 us; speedup vs baseline: 5.7186x; 1.2433x over previous
//
#include <hip/hip_runtime.h>
#include <math.h>

// SparseCoding, round 4.
// spec (32,128,256) fp32, basis (1024,256) fp32, n_iter=30, pad=0, stride=4 -> 63 windows.
// vs R3: FIX swizzled-coef layout collision (SW_S 260 -> 292; 260 < span 283 aliased
//        coef entries and corrupted the GEMM). Also: writer-side all-thread
//        __threadfence before the Gram barrier; tid0-only spin on the barrier.
#define NB     256
#define NF     128
#define FT     1024
#define NW     63
#define TORIG  256
#define MAXIT  48     // >= n_iter; sizes sync buffers
#define RPB    8      // batch rows per block
#define NBLK   4      // blocks per window
#define GRID   (NW * NBLK)   // 252 blocks; <= 256 so all co-resident at 1 block/CU

// swizzled coef layout: k = 32s + 4m + u, row b  ->  addr = s*SW_S + m*SW_M + b*4 + u
// injectivity: SW_S(292) > max(m*36+b*4+u)=283 ; SW_M(36) > max(b*4+u)=31 ; 4 > max u=3
#define SW_S 292
#define SW_M 36
#define SW_SZ (7*SW_S + 7*SW_M + 7*4 + 4)   // 2328 floats

__device__ __forceinline__ float rl(float v, int lane) {
    return __uint_as_float((unsigned)__builtin_amdgcn_readlane((int)__float_as_uint(v), lane));
}

__global__ __launch_bounds__(512, 2) void window_kernel(
    const float* __restrict__ spec,
    const float* __restrict__ basis,
    float* __restrict__ G,               // ws: 256x256
    const int* __restrict__ p_niter,
    const int* __restrict__ p_pad,
    const int* __restrict__ p_stride,
    double* __restrict__ sxbuf,          // [NW][NBLK]
    double* __restrict__ gpart,          // [MAXIT][NW][NBLK][2]
    unsigned int* __restrict__ gcnt,     // [MAXIT*NW] iter counters + [MAXIT*NW]=gbar (memset 0)
    float* __restrict__ out)             // (32,256,63)
{
    __shared__ float  s_part[RPB * RPB * 64 * 4];  // 64 KB  K-reduction exchange
    __shared__ float  s_xn[RPB * FT];              // 32 KB  normalized x
    __shared__ float  s_cf[SW_SZ];                 // 9.3 KB swizzled coef
    __shared__ float  s_gred[2][NB];               // Gram 2-way j-reduce
    __shared__ float  s_mn[RPB], s_rng[RPB];
    __shared__ double s_red[8][2];
    __shared__ int    s_stop;

    const int bid    = blockIdx.x;
    const int w      = bid >> 2;
    const int q      = bid & 3;
    const int tid    = threadIdx.x;
    const int ks     = tid >> 6;      // wave id: K-slice [32ks,32ks+32) AND local row ks
    const int kg     = tid & 63;      // lane: output cols 4kg..4kg+3
    const int n_iter = p_niter[0];
    const int t0     = w * p_stride[0] - p_pad[0];
    unsigned int* gbar = gcnt + MAXIT * NW;

    // ================= fused Gram: block bid computes G row(s) r =================
    for (int r = bid; r < NB; r += GRID) {
        const int c = tid & 255, jh = tid >> 8;
        float acc = 0.f;
        const float* bp = basis + (size_t)(jh * 512) * NB;
        #pragma unroll 16
        for (int j = 0; j < 512; ++j)
            acc = fmaf(bp[j * NB + r], bp[j * NB + c], acc);
        s_gred[jh][c] = acc;
        __syncthreads();
        if (jh == 0) G[(size_t)r * NB + c] = s_gred[0][c] + s_gred[1][c];
        __syncthreads();
    }
    __threadfence();               // every wave: agent-release its own G stores (wbl2)
    __syncthreads();
    if (tid == 0) atomicAdd(gbar, 1u);

    // ================= stage raw window, min/max, normalize ======================
    #pragma unroll
    for (int i = 0; i < 16; ++i) {
        const int e = i * 512 + tid;
        const int b = e >> 10, jj = e & 1023;
        const int f = jj >> 3, t = jj & 7, tq = t0 + t;
        s_xn[b * FT + jj] = (tq >= 0 && tq < TORIG)
            ? spec[((size_t)(q * RPB + b) * NF + f) * TORIG + tq] : 0.f;
    }
    __syncthreads();
    {   // wave ks scans row ks
        float mn = __builtin_inff(), mx = -__builtin_inff();
        #pragma unroll
        for (int i = 0; i < 16; ++i) {
            const float v = s_xn[ks * FT + i * 64 + kg];
            mn = fminf(mn, v); mx = fmaxf(mx, v);
        }
        #pragma unroll
        for (int off = 32; off; off >>= 1) {
            mn = fminf(mn, __shfl_down(mn, off));
            mx = fmaxf(mx, __shfl_down(mx, off));
        }
        if (kg == 0) { s_mn[ks] = mn; s_rng[ks] = mx - mn; }
    }
    __syncthreads();
    double sx2p = 0.0;
    #pragma unroll
    for (int i = 0; i < 16; ++i) {
        const int e = i * 512 + tid;
        const int b = e >> 10, jj = e & 1023;
        const float v = (s_xn[b * FT + jj] - s_mn[b]) / s_rng[b];   // exact div, matches ref
        s_xn[b * FT + jj] = v;
        sx2p += (double)v * (double)v;
    }
    #pragma unroll
    for (int off = 32; off; off >>= 1) sx2p += __shfl_down(sx2p, off);
    if (kg == 0) s_red[ks][0] = sx2p;
    __syncthreads();                       // s_xn normalized + s_red ready
    if (tid == 0) {
        double s = 0.0;
        #pragma unroll
        for (int i = 0; i < 8; ++i) s += s_red[i][0];
        sxbuf[w * NBLK + q] = s;           // released by the it=0 fence+atomic later
    }

    // ================= xB = xnorm @ basis (K-split partials + LDS reduce) ========
    float xbp[RPB][4];
    #pragma unroll
    for (int b = 0; b < RPB; ++b)
        #pragma unroll
        for (int j = 0; j < 4; ++j) xbp[b][j] = 0.f;
    for (int i0 = 0; i0 < 128; i0 += 4) {
        const int jj = ks * 128 + i0;
        float4 bv[4];
        #pragma unroll
        for (int t = 0; t < 4; ++t)
            bv[t] = *(const float4*)(basis + (size_t)(jj + t) * NB + 4 * kg);
        #pragma unroll
        for (int b = 0; b < RPB; ++b) {
            const float4 x4 = *(const float4*)&s_xn[b * FT + jj];
            xbp[b][0] = fmaf(x4.x, bv[0].x, fmaf(x4.y, bv[1].x, fmaf(x4.z, bv[2].x, fmaf(x4.w, bv[3].x, xbp[b][0]))));
            xbp[b][1] = fmaf(x4.x, bv[0].y, fmaf(x4.y, bv[1].y, fmaf(x4.z, bv[2].y, fmaf(x4.w, bv[3].y, xbp[b][1]))));
            xbp[b][2] = fmaf(x4.x, bv[0].z, fmaf(x4.y, bv[1].z, fmaf(x4.z, bv[2].z, fmaf(x4.w, bv[3].z, xbp[b][2]))));
            xbp[b][3] = fmaf(x4.x, bv[0].w, fmaf(x4.y, bv[1].w, fmaf(x4.z, bv[2].w, fmaf(x4.w, bv[3].w, xbp[b][3]))));
        }
    }
    #pragma unroll
    for (int b = 0; b < RPB; ++b)
        *(float4*)&s_part[((ks * RPB + b) * 64 + kg) * 4] =
            make_float4(xbp[b][0], xbp[b][1], xbp[b][2], xbp[b][3]);
    __syncthreads();
    float xB[4] = {0.f, 0.f, 0.f, 0.f};
    #pragma unroll
    for (int k2 = 0; k2 < 8; ++k2) {
        const float4 p4 = *(const float4*)&s_part[((k2 * RPB + ks) * 64 + kg) * 4];
        xB[0] += p4.x; xB[1] += p4.y; xB[2] += p4.z; xB[3] += p4.w;
    }

    // ================= wait for G (tid0 spin, acquire invalidates caches) ========
    if (tid == 0) {
        while (__hip_atomic_load(gbar, __ATOMIC_ACQUIRE, __HIP_MEMORY_SCOPE_AGENT) < (unsigned)GRID)
            __builtin_amdgcn_s_sleep(1);
    }
    __syncthreads();
    float4 g[32];
    #pragma unroll
    for (int kl = 0; kl < 32; ++kl)
        g[kl] = *(const float4*)(G + (size_t)(32 * ks + kl) * NB + 4 * kg);

    // ================= init coef / Adam ==========================================
    const float C0 = 0.5f / 256.f;
    float cf[4] = {C0, C0, C0, C0}, m_[4] = {0, 0, 0, 0}, v_[4] = {0, 0, 0, 0};
    *(float4*)&s_cf[(kg >> 3) * SW_S + (kg & 7) * SW_M + ks * 4] = make_float4(C0, C0, C0, C0);
    if (tid == 0) s_stop = 0;
    float b1p = 1.f, b2p = 1.f, old_loss = 1e-10f;
    double sxtot = 0.0;
    const float c1 = 2.f / 32768.f, c2 = 0.2f / 8192.f;

    for (int it = 0; it < n_iter; ++it) {
        __syncthreads();            // s_cf writes visible; s_part free

        // ---- GEMM: one ds_read_b128 per thread + readlane broadcasts ----
        const float4 c4 = *(const float4*)&s_cf[ks * SW_S + (kg >> 3) * SW_M + (kg & 7) * 4];
        float pacc[RPB][4];
        #pragma unroll
        for (int b = 0; b < RPB; ++b)
            #pragma unroll
            for (int j = 0; j < 4; ++j) pacc[b][j] = 0.f;
        #pragma unroll
        for (int m = 0; m < 8; ++m) {
            const float4 ga = g[4 * m + 0], gb = g[4 * m + 1];
            const float4 gc = g[4 * m + 2], gd = g[4 * m + 3];
            #pragma unroll
            for (int b = 0; b < RPB; ++b) {
                const int L = m * 8 + b;     // lane holding coef[b][32ks+4m..+3]
                const float cx = rl(c4.x, L), cy = rl(c4.y, L);
                const float cz = rl(c4.z, L), cw = rl(c4.w, L);
                pacc[b][0] = fmaf(cx, ga.x, fmaf(cy, gb.x, fmaf(cz, gc.x, fmaf(cw, gd.x, pacc[b][0]))));
                pacc[b][1] = fmaf(cx, ga.y, fmaf(cy, gb.y, fmaf(cz, gc.y, fmaf(cw, gd.y, pacc[b][1]))));
                pacc[b][2] = fmaf(cx, ga.z, fmaf(cy, gb.z, fmaf(cz, gc.z, fmaf(cw, gd.z, pacc[b][2]))));
                pacc[b][3] = fmaf(cx, ga.w, fmaf(cy, gb.w, fmaf(cz, gc.w, fmaf(cw, gd.w, pacc[b][3]))));
            }
        }

        // ---- K-reduction through LDS ----
        #pragma unroll
        for (int b = 0; b < RPB; ++b)
            *(float4*)&s_part[((ks * RPB + b) * 64 + kg) * 4] =
                make_float4(pacc[b][0], pacc[b][1], pacc[b][2], pacc[b][3]);
        __syncthreads();
        float a4[4] = {0.f, 0.f, 0.f, 0.f};
        #pragma unroll
        for (int k2 = 0; k2 < 8; ++k2) {
            const float4 p4 = *(const float4*)&s_part[((k2 * RPB + ks) * 64 + kg) * 4];
            a4[0] += p4.x; a4[1] += p4.y; a4[2] += p4.z; a4[3] += p4.w;
        }

        // ---- loss partials (fp64) ----
        double qc = 0.0, rr = 0.0;
        #pragma unroll
        for (int j = 0; j < 4; ++j) {
            qc += (double)cf[j] * ((double)a4[j] - 2.0 * (double)xB[j]);
            rr += (double)fabsf(cf[j]);
        }
        #pragma unroll
        for (int off = 32; off; off >>= 1) {
            qc += __shfl_down(qc, off);
            rr += __shfl_down(rr, off);
        }
        if (kg == 0) { s_red[ks][0] = qc; s_red[ks][1] = rr; }
        __syncthreads();

        // ---- tid0: post iter-it partials, then consume iter-(it-1) (deferred sync) ----
        if (tid == 0) {
            double Q = 0.0, R = 0.0;
            #pragma unroll
            for (int i = 0; i < 8; ++i) { Q += s_red[i][0]; R += s_red[i][1]; }
            const size_t pb = ((size_t)it * NW + w) * NBLK;
            gpart[(pb + q) * 2 + 0] = Q;
            gpart[(pb + q) * 2 + 1] = R;
            __threadfence();
            atomicAdd(&gcnt[it * NW + w], 1u);
            int stop = 0;
            if (it > 0) {
                const size_t pbm = ((size_t)(it - 1) * NW + w) * NBLK;
                while (__hip_atomic_load(&gcnt[(it - 1) * NW + w], __ATOMIC_ACQUIRE,
                                         __HIP_MEMORY_SCOPE_AGENT) < (unsigned)NBLK)
                    __builtin_amdgcn_s_sleep(1);
                double Qt = 0.0, Rt = 0.0;
                #pragma unroll
                for (int i = 0; i < NBLK; ++i) {
                    Qt += gpart[(pbm + i) * 2 + 0];
                    Rt += gpart[(pbm + i) * 2 + 1];
                }
                if (it == 1)
                    sxtot = sxbuf[w * NBLK + 0] + sxbuf[w * NBLK + 1] +
                            sxbuf[w * NBLK + 2] + sxbuf[w * NBLK + 3];
                const float loss = (float)((Qt + sxtot) / 32768.0 + 0.2 * (Rt / 8192.0));
                const float stat = fabsf(old_loss - loss) / old_loss;
                old_loss = loss;
                stop = (stat < 1e-3f) ? 1 : 0;
            }
            s_stop = stop;
        }
        __syncthreads();
        if (s_stop) break;          // conv(it-1) gates update(it) — matches reference

        // ---- Adam update ----
        b1p *= 0.9f; b2p *= 0.999f;
        const float bc1 = 1.f - b1p, bc2 = 1.f - b2p;
        #pragma unroll
        for (int j = 0; j < 4; ++j) {
            const float c_ = cf[j];
            const float sgn = (c_ > 0.f) ? 1.f : ((c_ < 0.f) ? -1.f : 0.f);
            const float gg = c1 * (a4[j] - xB[j]) + c2 * sgn;
            m_[j] = 0.9f * m_[j] + 0.1f * gg;
            v_[j] = 0.999f * v_[j] + 0.001f * gg * gg;
            cf[j] = c_ - 1e-3f * (m_[j] / bc1) / (sqrtf(v_[j] / bc2) + 1e-8f);
        }
        *(float4*)&s_cf[(kg >> 3) * SW_S + (kg & 7) * SW_M + ks * 4] =
            make_float4(cf[0], cf[1], cf[2], cf[3]);
    }

    // ---- out[b][k][w], b = q*8+ks, k = 4kg+j ----
    #pragma unroll
    for (int j = 0; j < 4; ++j)
        out[((size_t)(q * RPB + ks) * NB + 4 * kg + j) * NW + w] = cf[j];
}

// ---------------------------------------------------------------------------
extern "C" void kernel_launch(void* const* d_in, const int* in_sizes, int n_in,
                              void* d_out, int out_size, void* d_ws, size_t ws_size,
                              hipStream_t stream)
{
    const float* spec   = (const float*)d_in[0];
    const float* basis  = (const float*)d_in[1];
    const int* p_niter  = (const int*)d_in[2];
    const int* p_pad    = (const int*)d_in[3];
    const int* p_stride = (const int*)d_in[4];
    float* out = (float*)d_out;

    char* ws = (char*)d_ws;
    float*        G     = (float*)ws;                                   // 256 KB
    double*       sxbuf = (double*)(ws + 262144);                       // 2016 B (pad 4 KB)
    double*       gpart = (double*)(ws + 262144 + 4096);                // 193536 B
    unsigned int* gcnt  = (unsigned int*)(ws + 262144 + 4096 + 193536); // (MAXIT*NW+1)*4

    hipMemsetAsync(gcnt, 0, (MAXIT * NW + 1) * sizeof(unsigned int), stream);
    window_kernel<<<dim3(GRID), dim3(512), 0, stream>>>(
        spec, basis, G, p_niter, p_pad, p_stride, sxbuf, gpart, gcnt, out);
}